// Round 4
// baseline (153.064 us; speedup 1.0000x reference)
//
#include <hip/hip_runtime.h>
#include <math.h>

#define SEQ 2048
#define NTOK 4096
#define DM 1024

typedef __bf16 bf16x8 __attribute__((ext_vector_type(8)));
typedef __bf16 bf16x4 __attribute__((ext_vector_type(4)));
typedef float  f32x4  __attribute__((ext_vector_type(4)));

__device__ __forceinline__ void gll16(const void* g, void* l) {
    __builtin_amdgcn_global_load_lds(
        (const __attribute__((address_space(1))) void*)g,
        (__attribute__((address_space(3))) void*)l, 16, 0, 0);
}

__device__ __forceinline__ f32x4 mfma16(bf16x8 a, bf16x8 b, f32x4 c) {
    return __builtin_amdgcn_mfma_f32_16x16x32_bf16(a, b, c, 0, 0, 0);
}

// ---------------------------------------------------------------------------
__global__ void rope_tables(float* __restrict__ ct, float* __restrict__ st) {
    int idx = blockIdx.x * 256 + threadIdx.x;    // 2048*64 total
    int s = idx >> 6, d = idx & 63;
    int e = d & 31;
    float invf = 1.0f / powf(10000.0f, (float)e / 32.0f);
    float ang  = (float)s * invf;  // fp32 rounding as in reference
    double a   = (double)ang;
    ct[s * 64 + d] = (float)cos(a);
    st[s * 64 + d] = (float)sin(a);
}

// ---------------------------------------------------------------------------
// merged fp32->bf16 conversion for hs + 4 weights
__global__ void conv_all(const float* __restrict__ hs, const float* __restrict__ wq,
                         const float* __restrict__ wk, const float* __restrict__ wv,
                         const float* __restrict__ wo, __bf16* hsb, __bf16* wqb,
                         __bf16* wkb, __bf16* wvb, __bf16* wob) {
    long i = (long)blockIdx.x * 256 + threadIdx.x;     // 4-element units
    const long H4 = (long)NTOK * DM / 4;               // 1048576
    const float* src; __bf16* dst; long off;
    if (i < H4) { src = hs; dst = hsb; off = i; }
    else {
        long t = i - H4;
        int wsel = (int)(t >> 18);                     // W4 = 262144 = 2^18
        off = t & ((1L << 18) - 1);
        switch (wsel) {
            case 0:  src = wq; dst = wqb; break;
            case 1:  src = wk; dst = wkb; break;
            case 2:  src = wv; dst = wvb; break;
            default: src = wo; dst = wob; break;
        }
    }
    float4 v = ((const float4*)src)[off];
    __bf16* o = dst + off * 4;
    o[0] = (__bf16)v.x; o[1] = (__bf16)v.y; o[2] = (__bf16)v.z; o[3] = (__bf16)v.w;
}

// ---------------------------------------------------------------------------
// C[M,N] = (A[M,K=1024] @ B[N,K]^T) * scale, optional fused RoPE.
// 128x128 tile, BK=64, 4 waves (2x2). global_load_lds(16B), granule-XOR swz.
// ---------------------------------------------------------------------------
template <typename OutT, bool ROPE>
__device__ __forceinline__ void gemm_core(const __bf16* __restrict__ A,
                                          const __bf16* __restrict__ B,
                                          OutT* __restrict__ C, int N, float scale,
                                          const float* __restrict__ ct,
                                          const float* __restrict__ st,
                                          long bm, long bn) {
    __shared__ __bf16 As[128 * 64];
    __shared__ __bf16 Bs[128 * 64];
    const int tid  = threadIdx.x;
    const int lane = tid & 63;
    const int wid  = tid >> 6;
    const int l15  = lane & 15, lg = lane >> 4;
    const int wr = (wid >> 1) * 64, wc = (wid & 1) * 64;

    f32x4 acc[4][4];
    #pragma unroll
    for (int i = 0; i < 4; ++i)
        #pragma unroll
        for (int j = 0; j < 4; ++j) acc[i][j] = 0;

    const int srow = tid >> 3;
    const int sgz  = (tid & 7) ^ (srow & 7);
    const __bf16* Ag = A + (bm + srow) * 1024 + sgz * 8;
    const __bf16* Bg = B + (bn + srow) * 1024 + sgz * 8;

    for (int k0 = 0; k0 < 1024; k0 += 64) {
        __syncthreads();
        #pragma unroll
        for (int r = 0; r < 4; ++r) {
            gll16(Ag + (long)r * 32 * 1024 + k0, &As[r * 2048 + tid * 8]);
            gll16(Bg + (long)r * 32 * 1024 + k0, &Bs[r * 2048 + tid * 8]);
        }
        __syncthreads();
        #pragma unroll
        for (int kc = 0; kc < 2; ++kc) {
            bf16x8 a[4], b[4];
            #pragma unroll
            for (int i = 0; i < 4; ++i) {
                int R = wr + i * 16 + l15;
                a[i] = *(const bf16x8*)(As + R * 64 + (((kc * 4 + lg) ^ (R & 7)) * 8));
            }
            #pragma unroll
            for (int j = 0; j < 4; ++j) {
                int R = wc + j * 16 + l15;
                b[j] = *(const bf16x8*)(Bs + R * 64 + (((kc * 4 + lg) ^ (R & 7)) * 8));
            }
            #pragma unroll
            for (int i = 0; i < 4; ++i)
                #pragma unroll
                for (int j = 0; j < 4; ++j)
                    acc[i][j] = mfma16(a[i], b[j], acc[i][j]);
        }
    }

    if constexpr (ROPE) {
        #pragma unroll
        for (int i = 0; i < 4; ++i)
            #pragma unroll
            for (int j = 0; j < 2; ++j)
                #pragma unroll
                for (int r = 0; r < 4; ++r) {
                    long row = bm + wr + i * 16 + lg * 4 + r;
                    int  s   = (int)(row & (SEQ - 1));
                    int  d   = j * 16 + l15;
                    float c  = ct[s * 64 + d];
                    float sn = st[s * 64 + d];
                    float x0 = acc[i][j][r], x1 = acc[i][j + 2][r];
                    long col = bn + wc + j * 16 + l15;
                    C[row * N + col]      = (OutT)((x0 * c - x1 * sn) * scale);
                    C[row * N + col + 32] = (OutT)((x1 * c + x0 * sn) * scale);
                }
    } else {
        #pragma unroll
        for (int i = 0; i < 4; ++i)
            #pragma unroll
            for (int j = 0; j < 4; ++j)
                #pragma unroll
                for (int r = 0; r < 4; ++r) {
                    long row = bm + wr + i * 16 + lg * 4 + r;
                    long col = bn + wc + j * 16 + l15;
                    C[row * N + col] = (OutT)(acc[i][j][r] * scale);
                }
    }
}

// merged Q+K+V^T projections: z=0 Q (RoPE, *0.125), z=1 K (RoPE), z=2 V^T
__global__ __launch_bounds__(256) void gemm_qkv(const __bf16* __restrict__ hsb,
                                                const __bf16* __restrict__ wqb,
                                                const __bf16* __restrict__ wkb,
                                                const __bf16* __restrict__ wvb,
                                                __bf16* __restrict__ Qb,
                                                __bf16* __restrict__ Kb,
                                                __bf16* __restrict__ Vtb,
                                                const float* __restrict__ ct,
                                                const float* __restrict__ st) {
    if (blockIdx.z == 0)
        gemm_core<__bf16, true>(hsb, wqb, Qb, 1024, 0.125f, ct, st,
                                (long)blockIdx.y * 128, (long)blockIdx.x * 128);
    else if (blockIdx.z == 1)
        gemm_core<__bf16, true>(hsb, wkb, Kb, 1024, 1.0f, ct, st,
                                (long)blockIdx.y * 128, (long)blockIdx.x * 128);
    else
        gemm_core<__bf16, false>(wvb, hsb, Vtb, 4096, 1.0f, nullptr, nullptr,
                                 (long)blockIdx.x * 128, (long)blockIdx.y * 128);
}

template <typename OutT>
__global__ __launch_bounds__(256) void gemm_k(const __bf16* __restrict__ A,
                                              const __bf16* __restrict__ B,
                                              OutT* __restrict__ C, int N) {
    gemm_core<OutT, false>(A, B, C, N, 1.0f, nullptr, nullptr,
                           (long)blockIdx.y * 128, (long)blockIdx.x * 128);
}

// ---------------------------------------------------------------------------
// Flash attention: 8 waves x 16 q-rows (128-row q-tile), swapped QK^T,
// exp2-domain softmax with defer-max, double-buffered K/V via global_load_lds,
// wave-private P bounce, 1 barrier/iter. 512 thr -> 16 waves/CU (4/SIMD).
// ---------------------------------------------------------------------------
__global__ __launch_bounds__(512, 4) void flash3(const __bf16* __restrict__ Qb,
                                                 const __bf16* __restrict__ Kb,
                                                 const __bf16* __restrict__ Vt,
                                                 __bf16* __restrict__ Ob) {
    __shared__ __bf16 Ks[2][64 * 64];
    __shared__ __bf16 Vs[2][64 * 64];
    __shared__ __bf16 Ps[128 * 64];
    const int qt = blockIdx.x, h = blockIdx.y, b = blockIdx.z;
    const int tid = threadIdx.x, lane = tid & 63, w = tid >> 6;   // w 0..7
    const int l15 = lane & 15, lg = lane >> 4;

    // Q B-fragments, loaded once (Q pre-scaled by 0.125 in projection)
    const long qrow = (long)b * SEQ + qt * 128 + w * 16 + l15;
    const bf16x8 qf0 = *(const bf16x8*)(Qb + qrow * DM + h * 64 + lg * 8);
    const bf16x8 qf1 = *(const bf16x8*)(Qb + qrow * DM + h * 64 + 32 + lg * 8);

    f32x4 oacc[4];
    #pragma unroll
    for (int i = 0; i < 4; ++i) oacc[i] = 0;
    float m_run = -3e38f, l_run = 0.f;

    const int srow = tid >> 3;               // 0..63 -> full 64-row tile/call
    const int sgz  = (tid & 7) ^ (srow & 7);
    const __bf16* Kg = Kb + ((long)b * SEQ + srow) * DM + h * 64 + sgz * 8;
    const __bf16* Vg = Vt + ((long)h * 64 + srow) * NTOK + (long)b * SEQ + sgz * 8;

    auto stage = [&](int kt, int buf) {
        gll16(Kg + (long)(kt * 64) * DM, &Ks[buf][tid * 8]);
        gll16(Vg + kt * 64,              &Vs[buf][tid * 8]);
    };

    stage(0, 0);
    __syncthreads();

    const float L2E = 1.4426950408889634f;

    for (int kt = 0; kt < SEQ / 64; ++kt) {
        const int cur = kt & 1;
        if (kt < SEQ / 64 - 1) stage(kt + 1, cur ^ 1);   // prefetch next tile
        const __bf16* Kc = Ks[cur];
        const __bf16* Vc = Vs[cur];

        // QK^T (swapped): sc[j] = S^T[k = j*16+lg*4+r][q = l15]
        f32x4 sc[4];
        #pragma unroll
        for (int j = 0; j < 4; ++j) {
            int R = j * 16 + l15;
            bf16x8 ka0 = *(const bf16x8*)(Kc + R * 64 + ((lg       ^ (R & 7)) * 8));
            bf16x8 ka1 = *(const bf16x8*)(Kc + R * 64 + (((4 + lg) ^ (R & 7)) * 8));
            f32x4 z = 0;
            z = mfma16(ka0, qf0, z);
            z = mfma16(ka1, qf1, z);
            sc[j] = z;
        }

        // tile max for this q (16 local + 2 shfl over lg groups)
        float mx = fmaxf(fmaxf(sc[0][0], sc[0][1]), fmaxf(sc[0][2], sc[0][3]));
        #pragma unroll
        for (int j = 1; j < 4; ++j)
            mx = fmaxf(mx, fmaxf(fmaxf(sc[j][0], sc[j][1]), fmaxf(sc[j][2], sc[j][3])));
        mx = fmaxf(mx, __shfl_xor(mx, 16));
        mx = fmaxf(mx, __shfl_xor(mx, 32));

        // defer-max: rescale only when the running max grows (exact)
        if (mx > m_run) {
            float al = exp2f((m_run - mx) * L2E);
            m_run = mx;
            l_run *= al;
            #pragma unroll
            for (int i = 0; i < 4; ++i) oacc[i] *= al;
        }
        const float mL = m_run * L2E;

        // p = exp2(s*log2e - m*log2e); vectorized sum
        f32x4 rv = 0;
        #pragma unroll
        for (int j = 0; j < 4; ++j) {
            #pragma unroll
            for (int r = 0; r < 4; ++r)
                sc[j][r] = exp2f(__builtin_fmaf(sc[j][r], L2E, -mL));
            rv += sc[j];
        }
        float rs = (rv[0] + rv[1]) + (rv[2] + rv[3]);
        rs += __shfl_xor(rs, 16);
        rs += __shfl_xor(rs, 32);
        l_run += rs;

        // P -> LDS (packed b64, swizzled); rows wave-private: no barrier
        {
            int q = w * 16 + l15;
            #pragma unroll
            for (int j = 0; j < 4; ++j) {
                bf16x4 p4;
                p4[0] = (__bf16)sc[j][0]; p4[1] = (__bf16)sc[j][1];
                p4[2] = (__bf16)sc[j][2]; p4[3] = (__bf16)sc[j][3];
                int g16 = j * 2 + (lg >> 1);
                *(bf16x4*)(Ps + q * 64 + ((g16 ^ (q & 7)) * 8) + (lg & 1) * 4) = p4;
            }
        }

        // PV: O^T[d][q] += V^T[d][k] * P^T[k][q]
        #pragma unroll
        for (int kc = 0; kc < 2; ++kc) {
            int Rp = w * 16 + l15;
            bf16x8 pb = *(const bf16x8*)(Ps + Rp * 64 + (((kc * 4 + lg) ^ (Rp & 7)) * 8));
            #pragma unroll
            for (int i = 0; i < 4; ++i) {
                int Rv = i * 16 + l15;
                bf16x8 vb = *(const bf16x8*)(Vc + Rv * 64 + (((kc * 4 + lg) ^ (Rv & 7)) * 8));
                oacc[i] = mfma16(vb, pb, oacc[i]);
            }
        }

        __syncthreads();   // drains vmcnt (prefetch landed); buffers swap
    }

    // epilogue: O[tok][h*64+d] = O^T / l, packed 8B stores
    float linv = 1.0f / l_run;
    const long tok = (long)b * SEQ + qt * 128 + w * 16 + l15;
    #pragma unroll
    for (int i = 0; i < 4; ++i) {
        bf16x4 o4;
        #pragma unroll
        for (int r = 0; r < 4; ++r) o4[r] = (__bf16)(oacc[i][r] * linv);
        *(bf16x4*)(Ob + tok * DM + h * 64 + i * 16 + lg * 4) = o4;
    }
}

// ---------------------------------------------------------------------------
extern "C" void kernel_launch(void* const* d_in, const int* in_sizes, int n_in,
                              void* d_out, int out_size, void* d_ws, size_t ws_size,
                              hipStream_t stream) {
    const float* hs = (const float*)d_in[0];
    const float* wq = (const float*)d_in[1];
    const float* wk = (const float*)d_in[2];
    const float* wv = (const float*)d_in[3];
    const float* wo = (const float*)d_in[4];
    float* out = (float*)d_out;

    __bf16* hsb = (__bf16*)d_ws;
    __bf16* wqb = hsb + (long)NTOK * DM;
    __bf16* wkb = wqb + DM * DM;
    __bf16* wvb = wkb + DM * DM;
    __bf16* wob = wvb + DM * DM;
    __bf16* Qb  = wob + DM * DM;                 // attn out aliases Qb (disjoint)
    __bf16* Kb  = Qb + (long)NTOK * DM;
    __bf16* Vtb = Kb + (long)NTOK * DM;          // V^T: [1024][4096]
    float*  ct  = (float*)(Vtb + (long)NTOK * DM);
    float*  st  = ct + SEQ * 64;

    rope_tables<<<dim3(SEQ * 64 / 256), 256, 0, stream>>>(ct, st);
    conv_all<<<dim3(8192), 256, 0, stream>>>(hs, wq, wk, wv, wo,
                                             hsb, wqb, wkb, wvb, wob);

    // Q,K (RoPE fused) + V^T in one launch: 768 blocks = 3/CU
    gemm_qkv<<<dim3(8, 32, 3), 256, 0, stream>>>(hsb, wqb, wkb, wvb,
                                                 Qb, Kb, Vtb, ct, st);

    flash3<<<dim3(SEQ / 128, 16, 2), 512, 0, stream>>>(Qb, Kb, Vtb, Qb);

    // out = attn @ wo^T (fp32 out)
    gemm_k<float><<<dim3(8, 32), 256, 0, stream>>>(Qb, wob, out, 1024);
}